// Round 1
// baseline (574.161 us; speedup 1.0000x reference)
//
#include <hip/hip_runtime.h>
#include <hip/hip_bf16.h>
#include <math.h>

#define N_NODES 50000
#define N_EDGES 800000
#define C 64
#define EPS_F 1.000001f

// ---------------------------------------------------------------------------
// Kernel A: per-node precompute.
// One wave (64 lanes) per node row; lane = output channel.
//   xm_l = x @ w_l ; xm_u = x @ w_u ; out = (x @ w_lin) * EPS
//   s_src_* = xm_* @ a_*[:64] ; s_tgt_* = xm_* @ a_*[64:]
// Weights staged in LDS (3 * 16 KB + 2 * 512 B = ~49 KB -> ~3 blocks/CU, fine:
// this kernel is a tiny fraction of total time).
// ---------------------------------------------------------------------------
__global__ __launch_bounds__(256) void precompute_kernel(
    const float* __restrict__ x,
    const float* __restrict__ w_l, const float* __restrict__ a_l,
    const float* __restrict__ w_u, const float* __restrict__ a_u,
    const float* __restrict__ w_lin,
    float* __restrict__ xm_l, float* __restrict__ xm_u,
    float* __restrict__ s_src_l, float* __restrict__ s_tgt_l,
    float* __restrict__ s_src_u, float* __restrict__ s_tgt_u,
    float* __restrict__ out)
{
    __shared__ float lw_l[C * C];
    __shared__ float lw_u[C * C];
    __shared__ float lw_n[C * C];
    __shared__ float la_l[2 * C];
    __shared__ float la_u[2 * C];

    const int t = threadIdx.x;
    for (int idx = t; idx < C * C; idx += 256) {
        lw_l[idx] = w_l[idx];
        lw_u[idx] = w_u[idx];
        lw_n[idx] = w_lin[idx];
    }
    if (t < 2 * C) { la_l[t] = a_l[t]; la_u[t] = a_u[t]; }
    __syncthreads();

    const int wave = t >> 6;
    const int lane = t & 63;
    const int row = blockIdx.x * 4 + wave;
    if (row >= N_NODES) return;

    const float xv = x[row * C + lane];

    float acc_l = 0.f, acc_u = 0.f, acc_n = 0.f;
#pragma unroll
    for (int k = 0; k < C; ++k) {
        const float xk = __shfl(xv, k);
        acc_l = fmaf(xk, lw_l[k * C + lane], acc_l);
        acc_u = fmaf(xk, lw_u[k * C + lane], acc_u);
        acc_n = fmaf(xk, lw_n[k * C + lane], acc_n);
    }

    xm_l[row * C + lane] = acc_l;
    xm_u[row * C + lane] = acc_u;
    out[row * C + lane] = acc_n * EPS_F;   // init accumulator with skip branch

    // attention scalars: wave reduce over channels
    float ssl = acc_l * la_l[lane];
    float stl = acc_l * la_l[C + lane];
    float ssu = acc_u * la_u[lane];
    float stu = acc_u * la_u[C + lane];
#pragma unroll
    for (int off = 32; off >= 1; off >>= 1) {
        ssl += __shfl_xor(ssl, off);
        stl += __shfl_xor(stl, off);
        ssu += __shfl_xor(ssu, off);
        stu += __shfl_xor(stu, off);
    }
    if (lane == 0) {
        s_src_l[row] = ssl;
        s_tgt_l[row] = stl;
        s_src_u[row] = ssu;
        s_tgt_u[row] = stu;
    }
}

// ---------------------------------------------------------------------------
// Kernel B: edge scatter. One wave per edge; lane = channel.
//   i = idx[e] (target), j = idx[E+e] (source)
//   alpha = elu(s_src[j] + s_tgt[i]) * val[e]
//   out[i, lane] += alpha * xm[j, lane]   (atomic)
// ---------------------------------------------------------------------------
__global__ __launch_bounds__(256) void edge_kernel(
    const int* __restrict__ idx,
    const float* __restrict__ vals,
    const float* __restrict__ s_src, const float* __restrict__ s_tgt,
    const float* __restrict__ xm,
    float* __restrict__ out)
{
    const int e = (int)((blockIdx.x * (unsigned)blockDim.x + threadIdx.x) >> 6);
    const int lane = threadIdx.x & 63;
    if (e >= N_EDGES) return;

    const int i = idx[e];             // target
    const int j = idx[N_EDGES + e];   // source

    float a = s_src[j] + s_tgt[i];
    a = (a > 0.f) ? a : expm1f(a);    // elu, alpha=1
    a *= vals[e];

    const float msg = a * xm[j * C + lane];
    atomicAdd(&out[i * C + lane], msg);
}

// ---------------------------------------------------------------------------
// Kernel C: in-place ReLU on the accumulated output.
// ---------------------------------------------------------------------------
__global__ __launch_bounds__(256) void relu_kernel(float* __restrict__ out, int n)
{
    const int i = blockIdx.x * 256 + threadIdx.x;
    if (i < n) {
        const float v = out[i];
        out[i] = v > 0.f ? v : 0.f;
    }
}

extern "C" void kernel_launch(void* const* d_in, const int* in_sizes, int n_in,
                              void* d_out, int out_size, void* d_ws, size_t ws_size,
                              hipStream_t stream)
{
    const float* x          = (const float*)d_in[0];
    const int*   lower_idx  = (const int*)d_in[1];
    const float* lower_vals = (const float*)d_in[2];
    const int*   upper_idx  = (const int*)d_in[3];
    const float* upper_vals = (const float*)d_in[4];
    const float* w_lower    = (const float*)d_in[5];
    const float* a_lower    = (const float*)d_in[6];
    const float* w_upper    = (const float*)d_in[7];
    const float* a_upper    = (const float*)d_in[8];
    const float* w_lin      = (const float*)d_in[9];

    float* out = (float*)d_out;
    float* ws  = (float*)d_ws;

    // workspace layout (floats): xm_l[N*C], xm_u[N*C], ssl[N], stl[N], ssu[N], stu[N]
    float* xm_l = ws;
    float* xm_u = xm_l + (size_t)N_NODES * C;
    float* ssl  = xm_u + (size_t)N_NODES * C;
    float* stl  = ssl + N_NODES;
    float* ssu  = stl + N_NODES;
    float* stu  = ssu + N_NODES;

    // A: per-node precompute (4 rows/block)
    precompute_kernel<<<(N_NODES + 3) / 4, 256, 0, stream>>>(
        x, w_lower, a_lower, w_upper, a_upper, w_lin,
        xm_l, xm_u, ssl, stl, ssu, stu, out);

    // B: edge scatters (one wave per edge, 4 edges/block)
    const int edge_blocks = (N_EDGES + 3) / 4;
    edge_kernel<<<edge_blocks, 256, 0, stream>>>(lower_idx, lower_vals, ssl, stl, xm_l, out);
    edge_kernel<<<edge_blocks, 256, 0, stream>>>(upper_idx, upper_vals, ssu, stu, xm_u, out);

    // C: ReLU in place
    relu_kernel<<<(N_NODES * C + 255) / 256, 256, 0, stream>>>(out, N_NODES * C);
}

// Round 2
// 497.729 us; speedup vs baseline: 1.1536x; 1.1536x over previous
//
#include <hip/hip_runtime.h>
#include <hip/hip_bf16.h>
#include <math.h>

#define N_NODES 50000
#define N_EDGES 800000
#define C 64
#define EPS_F 1.000001f

// ---------------------------------------------------------------------------
// Kernel A: per-node precompute. One wave per 4 node rows (amortize LDS reads).
//   xm_l = x @ w_l ; xm_u = x @ w_u ; xlin = (x @ w_lin) * EPS
//   s_src_* = xm_* @ a_*[:64] ; s_tgt_* = xm_* @ a_*[64:]
// ---------------------------------------------------------------------------
__global__ __launch_bounds__(256) void precompute_kernel(
    const float* __restrict__ x,
    const float* __restrict__ w_l, const float* __restrict__ a_l,
    const float* __restrict__ w_u, const float* __restrict__ a_u,
    const float* __restrict__ w_lin,
    float* __restrict__ xm_l, float* __restrict__ xm_u,
    float* __restrict__ s_src_l, float* __restrict__ s_tgt_l,
    float* __restrict__ s_src_u, float* __restrict__ s_tgt_u,
    float* __restrict__ xlin)
{
    __shared__ float lw_l[C * C];
    __shared__ float lw_u[C * C];
    __shared__ float lw_n[C * C];
    __shared__ float la_l[2 * C];
    __shared__ float la_u[2 * C];

    const int t = threadIdx.x;
    for (int idx = t; idx < C * C; idx += 256) {
        lw_l[idx] = w_l[idx];
        lw_u[idx] = w_u[idx];
        lw_n[idx] = w_lin[idx];
    }
    if (t < 2 * C) { la_l[t] = a_l[t]; la_u[t] = a_u[t]; }
    __syncthreads();

    const int wave = t >> 6;
    const int lane = t & 63;
    const int row0 = (blockIdx.x * 4 + wave) * 4;   // 4 rows per wave

    float xv[4];
#pragma unroll
    for (int r = 0; r < 4; ++r) {
        const int row = row0 + r;
        xv[r] = (row < N_NODES) ? x[row * C + lane] : 0.f;
    }

    float acc_l[4] = {0.f, 0.f, 0.f, 0.f};
    float acc_u[4] = {0.f, 0.f, 0.f, 0.f};
    float acc_n[4] = {0.f, 0.f, 0.f, 0.f};

#pragma unroll 16
    for (int k = 0; k < C; ++k) {
        const float wl = lw_l[k * C + lane];
        const float wu = lw_u[k * C + lane];
        const float wn = lw_n[k * C + lane];
#pragma unroll
        for (int r = 0; r < 4; ++r) {
            const float xk = __shfl(xv[r], k);
            acc_l[r] = fmaf(xk, wl, acc_l[r]);
            acc_u[r] = fmaf(xk, wu, acc_u[r]);
            acc_n[r] = fmaf(xk, wn, acc_n[r]);
        }
    }

#pragma unroll
    for (int r = 0; r < 4; ++r) {
        const int row = row0 + r;
        if (row >= N_NODES) break;
        xm_l[row * C + lane] = acc_l[r];
        xm_u[row * C + lane] = acc_u[r];
        xlin[row * C + lane] = acc_n[r] * EPS_F;

        float ssl = acc_l[r] * la_l[lane];
        float stl = acc_l[r] * la_l[C + lane];
        float ssu = acc_u[r] * la_u[lane];
        float stu = acc_u[r] * la_u[C + lane];
#pragma unroll
        for (int off = 32; off >= 1; off >>= 1) {
            ssl += __shfl_xor(ssl, off);
            stl += __shfl_xor(stl, off);
            ssu += __shfl_xor(ssu, off);
            stu += __shfl_xor(stu, off);
        }
        if (lane == 0) {
            s_src_l[row] = ssl;
            s_tgt_l[row] = stl;
            s_src_u[row] = ssu;
            s_tgt_u[row] = stu;
        }
    }
}

// ---------------------------------------------------------------------------
// Kernel B1: degree histogram for both convs (deg arrays pre-zeroed).
// ---------------------------------------------------------------------------
__global__ __launch_bounds__(256) void hist_kernel(
    const int* __restrict__ lidx, const int* __restrict__ uidx,
    int* __restrict__ deg_l, int* __restrict__ deg_u)
{
    const int g = blockIdx.x * 256 + threadIdx.x;
    if (g >= 2 * N_EDGES) return;
    if (g < N_EDGES) atomicAdd(&deg_l[lidx[g]], 1);
    else             atomicAdd(&deg_u[uidx[g - N_EDGES]], 1);
}

// ---------------------------------------------------------------------------
// Kernel B2: exclusive scan deg -> off (N+1), and init cursor = off.
// One 1024-thread block per conv (grid = 2).
// ---------------------------------------------------------------------------
__global__ __launch_bounds__(1024) void scan_kernel(
    const int* __restrict__ deg_l, int* __restrict__ off_l, int* __restrict__ cur_l,
    const int* __restrict__ deg_u, int* __restrict__ off_u, int* __restrict__ cur_u)
{
    const int* deg = (blockIdx.x == 0) ? deg_l : deg_u;
    int* off = (blockIdx.x == 0) ? off_l : off_u;
    int* cur = (blockIdx.x == 0) ? cur_l : cur_u;

    __shared__ int sums[1024];
    const int t = threadIdx.x;
    const int chunk = (N_NODES + 1023) >> 10;           // 49
    const int s0 = t * chunk;
    const int s1 = min(s0 + chunk, N_NODES);

    int s = 0;
    for (int i = s0; i < s1; ++i) s += deg[i];
    sums[t] = s;
    __syncthreads();

    // inclusive Hillis-Steele scan over 1024 partials
    for (int o = 1; o < 1024; o <<= 1) {
        int v = (t >= o) ? sums[t - o] : 0;
        __syncthreads();
        sums[t] += v;
        __syncthreads();
    }

    int base = (t == 0) ? 0 : sums[t - 1];
    for (int i = s0; i < s1; ++i) {
        off[i] = base;
        cur[i] = base;
        base += deg[i];
    }
    if (t == 1023) off[N_NODES] = sums[1023];
}

// ---------------------------------------------------------------------------
// Kernel B3: CSR fill for both convs. Per edge: compute alpha, claim a slot
// under target i, store {source j (bits), alpha} as float2.
// ---------------------------------------------------------------------------
__global__ __launch_bounds__(256) void fill_kernel(
    const int* __restrict__ lidx, const float* __restrict__ lval,
    const float* __restrict__ ssl, const float* __restrict__ stl,
    int* __restrict__ cur_l, float2* __restrict__ rec_l,
    const int* __restrict__ uidx, const float* __restrict__ uval,
    const float* __restrict__ ssu, const float* __restrict__ stu,
    int* __restrict__ cur_u, float2* __restrict__ rec_u)
{
    const int g = blockIdx.x * 256 + threadIdx.x;
    if (g >= 2 * N_EDGES) return;

    if (g < N_EDGES) {
        const int e = g;
        const int i = lidx[e];
        const int j = lidx[N_EDGES + e];
        float s = ssl[j] + stl[i];
        s = (s > 0.f) ? s : expm1f(s);
        const float a = s * lval[e];
        const int slot = atomicAdd(&cur_l[i], 1);
        rec_l[slot] = make_float2(__int_as_float(j), a);
    } else {
        const int e = g - N_EDGES;
        const int i = uidx[e];
        const int j = uidx[N_EDGES + e];
        float s = ssu[j] + stu[i];
        s = (s > 0.f) ? s : expm1f(s);
        const float a = s * uval[e];
        const int slot = atomicAdd(&cur_u[i], 1);
        rec_u[slot] = make_float2(__int_as_float(j), a);
    }
}

// ---------------------------------------------------------------------------
// Kernel D: gather + fuse. One wave per node; lane = channel.
//   out[i] = relu( xlin[i] + sum_lower alpha*xm_l[j] + sum_upper alpha*xm_u[j] )
// ---------------------------------------------------------------------------
__global__ __launch_bounds__(256) void gather_kernel(
    const float* __restrict__ xlin,
    const int* __restrict__ off_l, const float2* __restrict__ rec_l,
    const float* __restrict__ xm_l,
    const int* __restrict__ off_u, const float2* __restrict__ rec_u,
    const float* __restrict__ xm_u,
    float* __restrict__ out)
{
    const int node = blockIdx.x * 4 + (threadIdx.x >> 6);
    const int lane = threadIdx.x & 63;
    if (node >= N_NODES) return;

    float acc = xlin[node * C + lane];

    {
        const int b = off_l[node], e = off_l[node + 1];
        int k = b;
        for (; k + 1 < e; k += 2) {
            const float2 r0 = rec_l[k];
            const float2 r1 = rec_l[k + 1];
            const float v0 = xm_l[__float_as_int(r0.x) * C + lane];
            const float v1 = xm_l[__float_as_int(r1.x) * C + lane];
            acc = fmaf(r0.y, v0, acc);
            acc = fmaf(r1.y, v1, acc);
        }
        if (k < e) {
            const float2 r0 = rec_l[k];
            acc = fmaf(r0.y, xm_l[__float_as_int(r0.x) * C + lane], acc);
        }
    }
    {
        const int b = off_u[node], e = off_u[node + 1];
        int k = b;
        for (; k + 1 < e; k += 2) {
            const float2 r0 = rec_u[k];
            const float2 r1 = rec_u[k + 1];
            const float v0 = xm_u[__float_as_int(r0.x) * C + lane];
            const float v1 = xm_u[__float_as_int(r1.x) * C + lane];
            acc = fmaf(r0.y, v0, acc);
            acc = fmaf(r1.y, v1, acc);
        }
        if (k < e) {
            const float2 r0 = rec_u[k];
            acc = fmaf(r0.y, xm_u[__float_as_int(r0.x) * C + lane], acc);
        }
    }

    out[node * C + lane] = fmaxf(acc, 0.f);
}

extern "C" void kernel_launch(void* const* d_in, const int* in_sizes, int n_in,
                              void* d_out, int out_size, void* d_ws, size_t ws_size,
                              hipStream_t stream)
{
    const float* x          = (const float*)d_in[0];
    const int*   lower_idx  = (const int*)d_in[1];
    const float* lower_vals = (const float*)d_in[2];
    const int*   upper_idx  = (const int*)d_in[3];
    const float* upper_vals = (const float*)d_in[4];
    const float* w_lower    = (const float*)d_in[5];
    const float* a_lower    = (const float*)d_in[6];
    const float* w_upper    = (const float*)d_in[7];
    const float* a_upper    = (const float*)d_in[8];
    const float* w_lin      = (const float*)d_in[9];

    float* out = (float*)d_out;
    char* ws = (char*)d_ws;

    // ---- workspace layout ----
    const size_t NC = (size_t)N_NODES * C * sizeof(float);   // 12.8 MB
    float* xm_l = (float*)ws;                 ws += NC;
    float* xm_u = (float*)ws;                 ws += NC;
    float* xlin = (float*)ws;                 ws += NC;
    float* ssl  = (float*)ws;                 ws += N_NODES * sizeof(float);
    float* stl  = (float*)ws;                 ws += N_NODES * sizeof(float);
    float* ssu  = (float*)ws;                 ws += N_NODES * sizeof(float);
    float* stu  = (float*)ws;                 ws += N_NODES * sizeof(float);
    int* deg_l  = (int*)ws;                   ws += N_NODES * sizeof(int);
    int* deg_u  = (int*)ws;                   ws += N_NODES * sizeof(int);   // adjacent to deg_l: one memset
    int* off_l  = (int*)ws;                   ws += (N_NODES + 1) * sizeof(int);
    int* off_u  = (int*)ws;                   ws += (N_NODES + 1) * sizeof(int);
    int* cur_l  = (int*)ws;                   ws += N_NODES * sizeof(int);
    int* cur_u  = (int*)ws;                   ws += N_NODES * sizeof(int);
    ws = (char*)(((size_t)ws + 15) & ~(size_t)15);
    float2* rec_l = (float2*)ws;              ws += (size_t)N_EDGES * sizeof(float2);  // 6.4 MB
    float2* rec_u = (float2*)ws;              ws += (size_t)N_EDGES * sizeof(float2);

    // zero the degree histograms (deg_l and deg_u are contiguous)
    hipMemsetAsync(deg_l, 0, 2 * N_NODES * sizeof(int), stream);

    // A: per-node precompute (16 rows/block: 4 waves x 4 rows)
    precompute_kernel<<<(N_NODES + 15) / 16, 256, 0, stream>>>(
        x, w_lower, a_lower, w_upper, a_upper, w_lin,
        xm_l, xm_u, ssl, stl, ssu, stu, xlin);

    // B1: degree histogram (both convs)
    hist_kernel<<<(2 * N_EDGES + 255) / 256, 256, 0, stream>>>(
        lower_idx, upper_idx, deg_l, deg_u);

    // B2: scan -> offsets + cursors
    scan_kernel<<<2, 1024, 0, stream>>>(deg_l, off_l, cur_l, deg_u, off_u, cur_u);

    // B3: CSR fill with per-edge alpha
    fill_kernel<<<(2 * N_EDGES + 255) / 256, 256, 0, stream>>>(
        lower_idx, lower_vals, ssl, stl, cur_l, rec_l,
        upper_idx, upper_vals, ssu, stu, cur_u, rec_u);

    // D: gather + skip + relu
    gather_kernel<<<(N_NODES + 3) / 4, 256, 0, stream>>>(
        xlin, off_l, rec_l, xm_l, off_u, rec_u, xm_u, out);
}

// Round 3
// 385.800 us; speedup vs baseline: 1.4882x; 1.2901x over previous
//
#include <hip/hip_runtime.h>
#include <hip/hip_bf16.h>
#include <math.h>

#define N_NODES 50000
#define N_EDGES 800000
#define C 64
#define EPS_F 1.000001f
#define TWO_N (2 * N_NODES)
#define NB_SCAN ((TWO_N + 255) / 256)   // 391 blocks over combined deg array

// ---------------------------------------------------------------------------
// Kernel A: per-node precompute. One wave per 4 node rows (amortize LDS reads).
//   xm_l = x @ w_l ; xm_u = x @ w_u ; xlin = (x @ w_lin) * EPS
//   s_src_* = xm_* @ a_*[:64] ; s_tgt_* = xm_* @ a_*[64:]
// ---------------------------------------------------------------------------
__global__ __launch_bounds__(256) void precompute_kernel(
    const float* __restrict__ x,
    const float* __restrict__ w_l, const float* __restrict__ a_l,
    const float* __restrict__ w_u, const float* __restrict__ a_u,
    const float* __restrict__ w_lin,
    float* __restrict__ xm_l, float* __restrict__ xm_u,
    float* __restrict__ s_src_l, float* __restrict__ s_tgt_l,
    float* __restrict__ s_src_u, float* __restrict__ s_tgt_u,
    float* __restrict__ xlin)
{
    __shared__ float lw_l[C * C];
    __shared__ float lw_u[C * C];
    __shared__ float lw_n[C * C];
    __shared__ float la_l[2 * C];
    __shared__ float la_u[2 * C];

    const int t = threadIdx.x;
    for (int idx = t; idx < C * C; idx += 256) {
        lw_l[idx] = w_l[idx];
        lw_u[idx] = w_u[idx];
        lw_n[idx] = w_lin[idx];
    }
    if (t < 2 * C) { la_l[t] = a_l[t]; la_u[t] = a_u[t]; }
    __syncthreads();

    const int wave = t >> 6;
    const int lane = t & 63;
    const int row0 = (blockIdx.x * 4 + wave) * 4;   // 4 rows per wave

    float xv[4];
#pragma unroll
    for (int r = 0; r < 4; ++r) {
        const int row = row0 + r;
        xv[r] = (row < N_NODES) ? x[row * C + lane] : 0.f;
    }

    float acc_l[4] = {0.f, 0.f, 0.f, 0.f};
    float acc_u[4] = {0.f, 0.f, 0.f, 0.f};
    float acc_n[4] = {0.f, 0.f, 0.f, 0.f};

#pragma unroll 16
    for (int k = 0; k < C; ++k) {
        const float wl = lw_l[k * C + lane];
        const float wu = lw_u[k * C + lane];
        const float wn = lw_n[k * C + lane];
#pragma unroll
        for (int r = 0; r < 4; ++r) {
            const float xk = __shfl(xv[r], k);
            acc_l[r] = fmaf(xk, wl, acc_l[r]);
            acc_u[r] = fmaf(xk, wu, acc_u[r]);
            acc_n[r] = fmaf(xk, wn, acc_n[r]);
        }
    }

#pragma unroll
    for (int r = 0; r < 4; ++r) {
        const int row = row0 + r;
        if (row >= N_NODES) break;
        xm_l[row * C + lane] = acc_l[r];
        xm_u[row * C + lane] = acc_u[r];
        xlin[row * C + lane] = acc_n[r] * EPS_F;

        float ssl = acc_l[r] * la_l[lane];
        float stl = acc_l[r] * la_l[C + lane];
        float ssu = acc_u[r] * la_u[lane];
        float stu = acc_u[r] * la_u[C + lane];
#pragma unroll
        for (int off = 32; off >= 1; off >>= 1) {
            ssl += __shfl_xor(ssl, off);
            stl += __shfl_xor(stl, off);
            ssu += __shfl_xor(ssu, off);
            stu += __shfl_xor(stu, off);
        }
        if (lane == 0) {
            s_src_l[row] = ssl;
            s_tgt_l[row] = stl;
            s_src_u[row] = ssu;
            s_tgt_u[row] = stu;
        }
    }
}

// ---------------------------------------------------------------------------
// Kernel B1: degree histogram into the COMBINED deg array.
// deg[0..N) = lower targets, deg[N..2N) = upper targets. deg pre-zeroed.
// ---------------------------------------------------------------------------
__global__ __launch_bounds__(256) void hist_kernel(
    const int* __restrict__ lidx, const int* __restrict__ uidx,
    int* __restrict__ deg)
{
    const int g = blockIdx.x * 256 + threadIdx.x;
    if (g >= 2 * N_EDGES) return;
    if (g < N_EDGES) atomicAdd(&deg[lidx[g]], 1);
    else             atomicAdd(&deg[N_NODES + uidx[g - N_EDGES]], 1);
}

// ---------------------------------------------------------------------------
// Kernel S1: per-block sums of the combined deg array (256 elems/block).
// ---------------------------------------------------------------------------
__global__ __launch_bounds__(256) void block_sum_kernel(
    const int* __restrict__ deg, int* __restrict__ bsum)
{
    const int t = threadIdx.x;
    const int g = blockIdx.x * 256 + t;
    int v = (g < TWO_N) ? deg[g] : 0;
#pragma unroll
    for (int o = 32; o >= 1; o >>= 1) v += __shfl_xor(v, o);
    __shared__ int ws[4];
    if ((t & 63) == 0) ws[t >> 6] = v;
    __syncthreads();
    if (t == 0) bsum[blockIdx.x] = ws[0] + ws[1] + ws[2] + ws[3];
}

// ---------------------------------------------------------------------------
// Kernel S2: inclusive scan of the 391 block sums (single block of 512).
// ---------------------------------------------------------------------------
__global__ __launch_bounds__(512) void scan_bsum_kernel(int* __restrict__ bsum)
{
    __shared__ int s[512];
    const int t = threadIdx.x;
    s[t] = (t < NB_SCAN) ? bsum[t] : 0;
    __syncthreads();
    for (int o = 1; o < 512; o <<= 1) {
        const int y = (t >= o) ? s[t - o] : 0;
        __syncthreads();
        s[t] += y;
        __syncthreads();
    }
    if (t < NB_SCAN) bsum[t] = s[t];   // inclusive scan
}

// ---------------------------------------------------------------------------
// Kernel S3: apply — exclusive scan of deg into off[] and cur[].
// Block-level shuffle scan + scanned block-sum prefix.
// ---------------------------------------------------------------------------
__global__ __launch_bounds__(256) void scan_apply_kernel(
    const int* __restrict__ deg, const int* __restrict__ bscan,
    int* __restrict__ off, int* __restrict__ cur)
{
    const int b = blockIdx.x, t = threadIdx.x;
    const int g = b * 256 + t;
    const int lane = t & 63, wv = t >> 6;

    const int v = (g < TWO_N) ? deg[g] : 0;
    int x = v;
#pragma unroll
    for (int o = 1; o < 64; o <<= 1) {
        const int y = __shfl_up(x, o);
        if (lane >= o) x += y;
    }
    __shared__ int wsum[4];
    if (lane == 63) wsum[wv] = x;
    __syncthreads();
    int wpre = 0;
    for (int w = 0; w < wv; ++w) wpre += wsum[w];
    const int bpre = (b == 0) ? 0 : bscan[b - 1];
    const int ex = bpre + wpre + (x - v);
    if (g < TWO_N) { off[g] = ex; cur[g] = ex; }
    if (g == TWO_N - 1) off[TWO_N] = ex + v;
}

// ---------------------------------------------------------------------------
// Kernel B3: CSR fill into the combined rec[] (lower first, upper after).
// Per edge: alpha = elu(s_src[j]+s_tgt[i])*val; claim slot under target.
// ---------------------------------------------------------------------------
__global__ __launch_bounds__(256) void fill_kernel(
    const int* __restrict__ lidx, const float* __restrict__ lval,
    const float* __restrict__ ssl, const float* __restrict__ stl,
    const int* __restrict__ uidx, const float* __restrict__ uval,
    const float* __restrict__ ssu, const float* __restrict__ stu,
    int* __restrict__ cur, float2* __restrict__ rec)
{
    const int g = blockIdx.x * 256 + threadIdx.x;
    if (g >= 2 * N_EDGES) return;

    if (g < N_EDGES) {
        const int e = g;
        const int i = lidx[e];
        const int j = lidx[N_EDGES + e];
        float s = ssl[j] + stl[i];
        s = (s > 0.f) ? s : expm1f(s);
        const float a = s * lval[e];
        const int slot = atomicAdd(&cur[i], 1);
        rec[slot] = make_float2(__int_as_float(j), a);
    } else {
        const int e = g - N_EDGES;
        const int i = uidx[e];
        const int j = uidx[N_EDGES + e];
        float s = ssu[j] + stu[i];
        s = (s > 0.f) ? s : expm1f(s);
        const float a = s * uval[e];
        const int slot = atomicAdd(&cur[N_NODES + i], 1);
        rec[slot] = make_float2(__int_as_float(j), a);
    }
}

// ---------------------------------------------------------------------------
// Kernel D: gather + fuse. One wave per node; lane = channel.
//   out[i] = relu( xlin[i] + sum_lower alpha*xm_l[j] + sum_upper alpha*xm_u[j] )
// ---------------------------------------------------------------------------
__device__ __forceinline__ float gather_range(
    const float2* __restrict__ rec, const float* __restrict__ xm,
    int b, int e, int lane, float acc)
{
    int k = b;
    for (; k + 3 < e; k += 4) {
        const float2 r0 = rec[k];
        const float2 r1 = rec[k + 1];
        const float2 r2 = rec[k + 2];
        const float2 r3 = rec[k + 3];
        const float v0 = xm[__float_as_int(r0.x) * C + lane];
        const float v1 = xm[__float_as_int(r1.x) * C + lane];
        const float v2 = xm[__float_as_int(r2.x) * C + lane];
        const float v3 = xm[__float_as_int(r3.x) * C + lane];
        acc = fmaf(r0.y, v0, acc);
        acc = fmaf(r1.y, v1, acc);
        acc = fmaf(r2.y, v2, acc);
        acc = fmaf(r3.y, v3, acc);
    }
    for (; k < e; ++k) {
        const float2 r0 = rec[k];
        acc = fmaf(r0.y, xm[__float_as_int(r0.x) * C + lane], acc);
    }
    return acc;
}

__global__ __launch_bounds__(256) void gather_kernel(
    const float* __restrict__ xlin,
    const int* __restrict__ off, const float2* __restrict__ rec,
    const float* __restrict__ xm_l, const float* __restrict__ xm_u,
    float* __restrict__ out)
{
    const int node = blockIdx.x * 4 + (threadIdx.x >> 6);
    const int lane = threadIdx.x & 63;
    if (node >= N_NODES) return;

    float acc = xlin[node * C + lane];
    acc = gather_range(rec, xm_l, off[node], off[node + 1], lane, acc);
    acc = gather_range(rec, xm_u, off[N_NODES + node], off[N_NODES + node + 1], lane, acc);
    out[node * C + lane] = fmaxf(acc, 0.f);
}

extern "C" void kernel_launch(void* const* d_in, const int* in_sizes, int n_in,
                              void* d_out, int out_size, void* d_ws, size_t ws_size,
                              hipStream_t stream)
{
    const float* x          = (const float*)d_in[0];
    const int*   lower_idx  = (const int*)d_in[1];
    const float* lower_vals = (const float*)d_in[2];
    const int*   upper_idx  = (const int*)d_in[3];
    const float* upper_vals = (const float*)d_in[4];
    const float* w_lower    = (const float*)d_in[5];
    const float* a_lower    = (const float*)d_in[6];
    const float* w_upper    = (const float*)d_in[7];
    const float* a_upper    = (const float*)d_in[8];
    const float* w_lin      = (const float*)d_in[9];

    float* out = (float*)d_out;
    char* ws = (char*)d_ws;

    // ---- workspace layout ----
    const size_t NC = (size_t)N_NODES * C * sizeof(float);   // 12.8 MB
    float* xm_l = (float*)ws;                 ws += NC;
    float* xm_u = (float*)ws;                 ws += NC;
    float* xlin = (float*)ws;                 ws += NC;
    float* ssl  = (float*)ws;                 ws += N_NODES * sizeof(float);
    float* stl  = (float*)ws;                 ws += N_NODES * sizeof(float);
    float* ssu  = (float*)ws;                 ws += N_NODES * sizeof(float);
    float* stu  = (float*)ws;                 ws += N_NODES * sizeof(float);
    int* deg    = (int*)ws;                   ws += TWO_N * sizeof(int);
    int* off    = (int*)ws;                   ws += (TWO_N + 1) * sizeof(int);
    int* cur    = (int*)ws;                   ws += TWO_N * sizeof(int);
    int* bsum   = (int*)ws;                   ws += 512 * sizeof(int);
    ws = (char*)(((size_t)ws + 15) & ~(size_t)15);
    float2* rec = (float2*)ws;                ws += (size_t)(2 * N_EDGES) * sizeof(float2); // 12.8 MB

    // zero the combined degree histogram
    hipMemsetAsync(deg, 0, TWO_N * sizeof(int), stream);

    // A: per-node precompute (16 rows/block: 4 waves x 4 rows)
    precompute_kernel<<<(N_NODES + 15) / 16, 256, 0, stream>>>(
        x, w_lower, a_lower, w_upper, a_upper, w_lin,
        xm_l, xm_u, ssl, stl, ssu, stu, xlin);

    // B1: degree histogram (both convs, combined)
    hist_kernel<<<(2 * N_EDGES + 255) / 256, 256, 0, stream>>>(
        lower_idx, upper_idx, deg);

    // S1/S2/S3: multi-block exclusive scan -> off + cur
    block_sum_kernel<<<NB_SCAN, 256, 0, stream>>>(deg, bsum);
    scan_bsum_kernel<<<1, 512, 0, stream>>>(bsum);
    scan_apply_kernel<<<NB_SCAN, 256, 0, stream>>>(deg, bsum, off, cur);

    // B3: CSR fill with per-edge alpha (combined rec)
    fill_kernel<<<(2 * N_EDGES + 255) / 256, 256, 0, stream>>>(
        lower_idx, lower_vals, ssl, stl,
        upper_idx, upper_vals, ssu, stu,
        cur, rec);

    // D: gather + skip + relu
    gather_kernel<<<(N_NODES + 3) / 4, 256, 0, stream>>>(
        xlin, off, rec, xm_l, xm_u, out);
}